// Round 8
// baseline (103.457 us; speedup 1.0000x reference)
//
#include <hip/hip_runtime.h>

// Problem constants
#define BATCH 4
#define SEQ   2048
#define INC   512
#define NH    8
#define OUTC  64      // space dim; head dim = 65
#define DD    65
#define NROW  (BATCH * NH * SEQ)   // 65536

typedef float f32x4 __attribute__((ext_vector_type(4)));
typedef short short8 __attribute__((ext_vector_type(8)));
typedef short short4v __attribute__((ext_vector_type(4)));
typedef unsigned short us;

static __device__ __forceinline__ us f2b(float f) {
  unsigned int u = __float_as_uint(f);
  u = (u + 0x7FFFu + ((u >> 16) & 1u)) >> 16;   // RNE f32->bf16
  return (us)u;
}
static __device__ __forceinline__ float b2f(us h) {
  return __uint_as_float(((unsigned int)h) << 16);
}
static __device__ __forceinline__ unsigned int pk2(float lo, float hi) {
  unsigned int r;
  asm("v_cvt_pk_bf16_f32 %0, %1, %2" : "=v"(r) : "v"(lo), "v"(hi));
  return r;
}
static __device__ __forceinline__ short8 mk8(unsigned int a, unsigned int b,
                                             unsigned int c, unsigned int d) {
  union { unsigned int u[4]; short8 s; } x;
  x.u[0] = a; x.u[1] = b; x.u[2] = c; x.u[3] = d;
  return x.s;
}

#define GLDS(g, l) __builtin_amdgcn_global_load_lds( \
    (const __attribute__((address_space(1))) void*)(g), \
    (__attribute__((address_space(3))) void*)(l), 16, 0, 0)
#define SB() __builtin_amdgcn_sched_barrier(0)

// ---------------------------------------------------------------------------
// Kernel 0: f32 -> bf16 conversion for X (both) and W (all three).
// ---------------------------------------------------------------------------
__global__ __launch_bounds__(256) void tobf16_kernel(
    const float* __restrict__ Xq, const float* __restrict__ Xs,
    const float* __restrict__ Wq, const float* __restrict__ Wk,
    const float* __restrict__ Wv,
    us* __restrict__ dXq, us* __restrict__ dXs,
    us* __restrict__ dWq, us* __restrict__ dWk, us* __restrict__ dWv)
{
  const int which = blockIdx.y;
  const float* src;
  us* dst;
  int n;
  switch (which) {
    case 0: src = Xq; dst = dXq; n = BATCH * SEQ * INC; break;
    case 1: src = Xs; dst = dXs; n = BATCH * SEQ * INC; break;
    case 2: src = Wq; dst = dWq; n = NH * OUTC * INC; break;
    case 3: src = Wk; dst = dWk; n = NH * OUTC * INC; break;
    default: src = Wv; dst = dWv; n = NH * OUTC * INC; break;
  }
  for (long i = (long)blockIdx.x * 256 + threadIdx.x; i * 4 < n;
       i += (long)gridDim.x * 256) {
    f32x4 v = *(const f32x4*)(src + i * 4);
    short4v o;
    o[0] = (short)f2b(v[0]); o[1] = (short)f2b(v[1]);
    o[2] = (short)f2b(v[2]); o[3] = (short)f2b(v[3]);
    *(short4v*)(dst + i * 4) = o;
  }
}

// ---------------------------------------------------------------------------
// Kernel 1: per-head projections, GLDS double-buffered.
//   Q (which==0): space part PRE-SCALED by al2 = (2/scale)*log2e; qta u32
//                 packs (qh | ql<<16) of al2*t.
//   K (which==1): kta u32 = (-kh) | (-kl)<<16 (raw t).
//   V (which==2): vtc bf16 planes {hi, lo} of raw t.
// ---------------------------------------------------------------------------
__global__ __launch_bounds__(256) void proj_kernel(
    const us* __restrict__ Xqb, const us* __restrict__ Xsb,
    const us* __restrict__ Wqb, const us* __restrict__ Wkb, const us* __restrict__ Wvb,
    const float* __restrict__ Bq, const float* __restrict__ Bk, const float* __restrict__ Bv,
    const float* __restrict__ scale_p,
    us* __restrict__ qs, unsigned int* __restrict__ qta,
    us* __restrict__ ks, unsigned int* __restrict__ kta,
    us* __restrict__ vs, us* __restrict__ vtc)
{
  const int which = blockIdx.z;
  const us* X = (which == 0) ? Xqb : Xsb;
  const us* W = (which == 0) ? Wqb : (which == 1 ? Wkb : Wvb);
  const float* Bb = (which == 0) ? Bq : (which == 1 ? Bk : Bv);
  us* outs = (which == 0) ? qs : (which == 1 ? ks : vs);
  const float al2 = (2.0f / scale_p[0]) * 1.44269504088896f;
  const float oscale = (which == 0) ? al2 : 1.0f;

  const int lin = blockIdx.x;                    // 0..1023
  const int h   = (lin >> 3) & 7;
  const int m0  = (((lin >> 6) << 3) | (lin & 7)) * 64;
  const int n0  = h * 64;

  __shared__ alignas(16) us lX[2][64 * 64];
  __shared__ alignas(16) us lW[2][64 * 64];

  const int tid  = threadIdx.x;
  const int lane = tid & 63;
  const int wave = tid >> 6;
  const int arow = lane & 15;
  const int agrp = lane >> 4;
  const int rl   = lane >> 3;
  const int chx  = ((lane & 7) ^ rl) * 8;
  const int r0   = wave * 8 + rl;
  const int r1   = r0 + 32;

#define PSTAGE(buf, k0) do { \
    GLDS(X + (size_t)(m0 + r0) * INC + (k0) + chx, &lX[buf][wave * 512]); \
    GLDS(X + (size_t)(m0 + r1) * INC + (k0) + chx, &lX[buf][2048 + wave * 512]); \
    GLDS(W + (size_t)(n0 + r0) * INC + (k0) + chx, &lW[buf][wave * 512]); \
    GLDS(W + (size_t)(n0 + r1) * INC + (k0) + chx, &lW[buf][2048 + wave * 512]); \
  } while (0)

  f32x4 acc[4] = {};
  PSTAGE(0, 0);

  for (int kk = 0; kk < 8; ++kk) {
    const int cur = kk & 1;
    if (kk < 7) {
      PSTAGE(cur ^ 1, (kk + 1) * 64);
      asm volatile("s_waitcnt vmcnt(4)");
    } else {
      asm volatile("s_waitcnt vmcnt(0)");
    }
    __builtin_amdgcn_s_barrier();
#pragma unroll
    for (int kc = 0; kc < 2; ++kc) {
      short8 af = *(const short8*)&lX[cur][(wave * 16 + arow) * 64 + (((kc * 4 + agrp) ^ (arow & 7)) * 8)];
#pragma unroll
      for (int c = 0; c < 4; ++c) {
        short8 bf = *(const short8*)&lW[cur][(c * 16 + arow) * 64 + (((kc * 4 + agrp) ^ (arow & 7)) * 8)];
        acc[c] = __builtin_amdgcn_mfma_f32_16x16x32_bf16(af, bf, acc[c], 0, 0, 0);
      }
    }
    __builtin_amdgcn_s_barrier();
  }

  float bcol[4];
#pragma unroll
  for (int c = 0; c < 4; ++c) bcol[c] = Bb[n0 + c * 16 + arow];
#pragma unroll
  for (int r = 0; r < 4; ++r) {
    float s2 = 0.f;
#pragma unroll
    for (int c = 0; c < 4; ++c) {
      float v = acc[c][r] + bcol[c];
      acc[c][r] = v;
      s2 += v * v;
    }
    s2 += __shfl_xor(s2, 1); s2 += __shfl_xor(s2, 2);
    s2 += __shfl_xor(s2, 4); s2 += __shfl_xor(s2, 8);
    float tv = sqrtf(s2 + 1.0f);
    int gs = m0 + wave * 16 + agrp * 4 + r;
    int bi = gs >> 11, si = gs & (SEQ - 1);
    size_t rowbase = (size_t)(bi * NH + h) * SEQ + si;
    size_t obase = rowbase * 64;
#pragma unroll
    for (int c = 0; c < 4; ++c) outs[obase + c * 16 + arow] = f2b(oscale * acc[c][r]);
    if (arow == 0) {
      if (which == 0) {
        float st = al2 * tv;
        us qh = f2b(st);
        us ql = f2b(st - b2f(qh));
        qta[rowbase] = (unsigned int)qh | ((unsigned int)ql << 16);
      } else {
        us th = f2b(tv);
        us tl = f2b(tv - b2f(th));
        if (which == 1) {
          kta[rowbase] = (unsigned int)(us)(th ^ 0x8000)
                       | ((unsigned int)(us)(tl ^ 0x8000) << 16);
        } else {
          vtc[rowbase] = th;
          vtc[NROW + rowbase] = tl;
        }
      }
    }
  }
}

// ---------------------------------------------------------------------------
// Kernel 2: transpose V space-part per (b,h): [S,64] -> [64,S] with a
// PERMUTED k-order inside each 64-block: k' = g*16 + (c>>1)*8 + (c&1)*4 + r
// (c=k>>4, g=(k>>2)&3, r=k&3). This makes each lane's own QK^T outputs the
// PV A-fragment directly (in-register P), with V readable as b128 slices.
// ---------------------------------------------------------------------------
__global__ __launch_bounds__(256) void transpose_v_kernel(
    const us* __restrict__ vs, us* __restrict__ vT)
{
  const int bh = blockIdx.y;
  const int s0 = blockIdx.x * 64;
  __shared__ us lT[64 * 80];
  const int tid = threadIdx.x;
#pragma unroll
  for (int u0 = 0; u0 < 2; ++u0) {
    int u = tid + u0 * 256;
    int row = u >> 3, ch = u & 7;
    short8 v = *(const short8*)&vs[((size_t)bh * SEQ + s0 + row) * 64 + ch * 8];
    *(short8*)&lT[row * 80 + ch * 8] = v;
  }
  __syncthreads();
#pragma unroll
  for (int u0 = 0; u0 < 2; ++u0) {
    int u = tid + u0 * 256;
    int o = u >> 3, sc = u & 7;
    short4v w0, w1;
#pragma unroll
    for (int j = 0; j < 4; ++j) w0[j] = (short)lT[(sc * 8 + j) * 80 + o];
#pragma unroll
    for (int j = 0; j < 4; ++j) w1[j] = (short)lT[(sc * 8 + 4 + j) * 80 + o];
    const int base0 = (sc & 1) * 32 + (sc >> 2) * 8 + ((sc >> 1) & 1) * 4;
    us* dst = vT + ((size_t)bh * 64 + o) * SEQ + s0;
    *(short4v*)(dst + base0) = w0;
    *(short4v*)(dst + base0 + 16) = w1;
  }
}

// ---------------------------------------------------------------------------
// Kernel 3: causal flash attention. QBLK=128 (2 sets of 16 q-rows per wave,
// sharing all K/V LDS reads), KBLK=64, 4-way split-k, in-register P,
// pre-scaled Q (P = exp2(sS) directly). 1024 blocks, 32KB LDS.
// Partials [128 rows][68]: 64 space, tsum, lsum (m == 0 always -> exact sum
// merge in finalize).
// ---------------------------------------------------------------------------
__global__ __launch_bounds__(256) void attn_kernel(
    const us* __restrict__ qs, const unsigned int* __restrict__ qta,
    const us* __restrict__ ks, const unsigned int* __restrict__ kta,
    const us* __restrict__ vT, const us* __restrict__ vtc,
    float* __restrict__ part)
{
  const int f = blockIdx.x;
  const int xcd = f & 7, idx = f >> 3;
  const int bh = xcd * 4 + (idx >> 5);
  const int inner = idx & 31;
  const int x = inner >> 2;
  const int hf = inner & 3;

  __shared__ alignas(16) us lK[2][64 * 64];
  __shared__ alignas(16) us lV[2][64 * 64];

  const int tid  = threadIdx.x;
  const int lane = tid & 63;
  const int wave = tid >> 6;
  const int arow = lane & 15;
  const int agrp = lane >> 4;

  const size_t bhbase = (size_t)bh * SEQ;
  const us* kgp = ks + bhbase * 64;
  const us* vgp = vT + (size_t)bh * 64 * SEQ;
  const unsigned int* ktp = kta + bhbase;
  const us* vtp = vtc + (size_t)(arow & 1) * NROW + bhbase;

  const int rl    = lane >> 3;
  const int chx   = ((lane & 7) ^ rl) * 8;
  const int r0s   = wave * 8 + rl;
  const int r1s   = r0s + 32;
  const int dsl0  = (agrp ^ (arow & 7)) * 8;
  const int dsl1  = ((4 + agrp) ^ (arow & 7)) * 8;
  const int dslV0 = ((agrp * 2) ^ (arow & 7)) * 8;       // kc=0
  const int dslV1 = ((agrp * 2 + 1) ^ (arow & 7)) * 8;   // kc=1

#define ASTAGE(buf, t64) do { \
    const int kk = (t64) * 64; \
    GLDS(kgp + (size_t)(kk + r0s) * 64 + chx, &lK[buf][wave * 512]); \
    GLDS(kgp + (size_t)(kk + r1s) * 64 + chx, &lK[buf][2048 + wave * 512]); \
    GLDS(vgp + (size_t)r0s * SEQ + kk + chx, &lV[buf][wave * 512]); \
    GLDS(vgp + (size_t)r1s * SEQ + kk + chx, &lV[buf][2048 + wave * 512]); \
  } while (0)

  short8 ones8, zero8 = {};
#pragma unroll
  for (int j = 0; j < 8; ++j) ones8[j] = (short)0x3F80;

  for (int seg = 0; seg < 2; ++seg) {
    const int qT = seg ? (15 - x) : x;
    const int q0 = qT * 128;
    const int nk = 2 * qT + 2;
    const int nbase = nk >> 2, rem = nk & 3;
    const int nt = nbase + (hf < rem ? 1 : 0);
    const int t_lo = hf * nbase + (hf < rem ? hf : rem);

    f32x4 acc0[5] = {}, acc1[5] = {};

    if (nt > 0) {
      const int wq0 = q0 + wave * 16 + arow;       // set0 global q row
      const int wq1 = wq0 + 64;                    // set1

      // Q loads (6 VMEM)
      const us* qp0 = qs + (bhbase + wq0) * 64;
      const us* qp1 = qs + (bhbase + wq1) * 64;
      short8 qf00 = *(const short8*)(qp0 + agrp * 8);
      short8 qf01 = *(const short8*)(qp0 + 32 + agrp * 8);
      short8 qf10 = *(const short8*)(qp1 + agrp * 8);
      short8 qf11 = *(const short8*)(qp1 + 32 + agrp * 8);
      unsigned int qw0 = qta[bhbase + wq0];
      unsigned int qw1 = qta[bhbase + wq1];
      short8 qf2_0 = {}, qf2_1 = {};
      if (agrp == 0) {
        qf2_0[0] = (short)(qw0 & 0xFFFFu); qf2_0[1] = (short)(qw0 & 0xFFFFu);
        qf2_0[2] = (short)(qw0 >> 16);
        qf2_1[0] = (short)(qw1 & 0xFFFFu); qf2_1[1] = (short)(qw1 & 0xFFFFu);
        qf2_1[2] = (short)(qw1 >> 16);
      }

      // aug regs for first tile (8 VMEM)
      unsigned int ka[4];
      short4v vaA[2], vaB[2];
      {
        const int kk = t_lo * 64;
#pragma unroll
        for (int c = 0; c < 4; ++c) ka[c] = ktp[kk + c * 16 + arow];
#pragma unroll
        for (int kc = 0; kc < 2; ++kc) {
          vaA[kc] = *(const short4v*)(vtp + kk + kc * 32 + agrp * 4);
          vaB[kc] = *(const short4v*)(vtp + kk + kc * 32 + 16 + agrp * 4);
        }
      }
      SB();
      ASTAGE(0, t_lo);
      SB();

      for (int it = 0; it < nt; ++it) {
        const int t = t_lo + it;
        const int cur = it & 1;
        if (it < nt - 1) {
          ASTAGE(cur ^ 1, t + 1);
          SB();
          if (it == 0) asm volatile("s_waitcnt vmcnt(4)");
          else         asm volatile("s_waitcnt vmcnt(12)");
        } else {
          SB();
          if (nt > 1) asm volatile("s_waitcnt vmcnt(8)");
          else        asm volatile("s_waitcnt vmcnt(0)");
        }
        SB();
        __builtin_amdgcn_s_barrier();

        const us* Kb = lK[cur];
        const us* Vb = lV[cur];

        // ---- S^T = K' Q'^T for both q-sets (K fragments shared) ----
        f32x4 s0[4] = {}, s1[4] = {};
        __builtin_amdgcn_s_setprio(1);
#pragma unroll
        for (int c = 0; c < 4; ++c) {
          short8 kf = *(const short8*)&Kb[(c * 16 + arow) * 64 + dsl0];
          s0[c] = __builtin_amdgcn_mfma_f32_16x16x32_bf16(kf, qf00, s0[c], 0, 0, 0);
          s1[c] = __builtin_amdgcn_mfma_f32_16x16x32_bf16(kf, qf10, s1[c], 0, 0, 0);
        }
#pragma unroll
        for (int c = 0; c < 4; ++c) {
          short8 kf = *(const short8*)&Kb[(c * 16 + arow) * 64 + dsl1];
          s0[c] = __builtin_amdgcn_mfma_f32_16x16x32_bf16(kf, qf01, s0[c], 0, 0, 0);
          s1[c] = __builtin_amdgcn_mfma_f32_16x16x32_bf16(kf, qf11, s1[c], 0, 0, 0);
        }
#pragma unroll
        for (int c = 0; c < 4; ++c) {
          short8 kf2 = {};
          if (agrp == 0) {
            unsigned int w0 = ka[c];
            kf2[0] = (short)(w0 & 0xFFFFu);
            kf2[1] = (short)(w0 >> 16);
            kf2[2] = (short)(w0 & 0xFFFFu);
          }
          s0[c] = __builtin_amdgcn_mfma_f32_16x16x32_bf16(kf2, qf2_0, s0[c], 0, 0, 0);
          s1[c] = __builtin_amdgcn_mfma_f32_16x16x32_bf16(kf2, qf2_1, s1[c], 0, 0, 0);
        }
        __builtin_amdgcn_s_setprio(0);

        // ---- P = exp2(logit) (Q pre-scaled); mask -> exact 0 ----
#pragma unroll
        for (int c = 0; c < 4; ++c)
#pragma unroll
          for (int r = 0; r < 4; ++r) {
            s0[c][r] = exp2f(s0[c][r]);
            s1[c][r] = exp2f(s1[c][r]);
          }
        if (t >= 2 * qT) {
          const int kb = t * 64;
#pragma unroll
          for (int c = 0; c < 4; ++c)
#pragma unroll
            for (int r = 0; r < 4; ++r) {
              int k = kb + c * 16 + agrp * 4 + r;
              if (k > wq0) s0[c][r] = 0.f;
              if (k > wq1) s1[c][r] = 0.f;
            }
        }

        // ---- PV, in-register P (permuted V^T matches lane-local packing) --
        __builtin_amdgcn_s_setprio(1);
#pragma unroll
        for (int kc = 0; kc < 2; ++kc) {
          short8 pf0 = mk8(pk2(s0[2*kc][0], s0[2*kc][1]),
                           pk2(s0[2*kc][2], s0[2*kc][3]),
                           pk2(s0[2*kc+1][0], s0[2*kc+1][1]),
                           pk2(s0[2*kc+1][2], s0[2*kc+1][3]));
          short8 pf1 = mk8(pk2(s1[2*kc][0], s1[2*kc][1]),
                           pk2(s1[2*kc][2], s1[2*kc][3]),
                           pk2(s1[2*kc+1][0], s1[2*kc+1][1]),
                           pk2(s1[2*kc+1][2], s1[2*kc+1][3]));
          const int dsl = kc ? dslV1 : dslV0;
#pragma unroll
          for (int dc = 0; dc < 4; ++dc) {
            short8 vf = *(const short8*)&Vb[(dc * 16 + arow) * 64 + dsl];
            acc0[dc] = __builtin_amdgcn_mfma_f32_16x16x32_bf16(pf0, vf, acc0[dc], 0, 0, 0);
            acc1[dc] = __builtin_amdgcn_mfma_f32_16x16x32_bf16(pf1, vf, acc1[dc], 0, 0, 0);
          }
          short8 vf4;
          if (arow < 2) {
            *(short4v*)&vf4 = vaA[kc];
            *(((short4v*)&vf4) + 1) = vaB[kc];
          } else vf4 = (arow == 2) ? ones8 : zero8;
          acc0[4] = __builtin_amdgcn_mfma_f32_16x16x32_bf16(pf0, vf4, acc0[4], 0, 0, 0);
          acc1[4] = __builtin_amdgcn_mfma_f32_16x16x32_bf16(pf1, vf4, acc1[4], 0, 0, 0);
        }
        __builtin_amdgcn_s_setprio(0);

        // aug prefetch for next tile (in flight across the barrier)
        SB();
        if (it + 1 < nt) {
          const int kk = (t + 1) * 64;
#pragma unroll
          for (int c = 0; c < 4; ++c) ka[c] = ktp[kk + c * 16 + arow];
#pragma unroll
          for (int kc = 0; kc < 2; ++kc) {
            vaA[kc] = *(const short4v*)(vtp + kk + kc * 32 + agrp * 4);
            vaB[kc] = *(const short4v*)(vtp + kk + kc * 32 + 16 + agrp * 4);
          }
        }
        SB();
        __builtin_amdgcn_s_barrier();   // reads done: safe to overwrite other buf
      }
    }

    // ---- epilogue: un-normalized partials for both sets (zeros if empty) --
    const size_t pbase = (size_t)(((bh * 16 + qT) * 4 + hf)) * 128;
#pragma unroll
    for (int r = 0; r < 4; ++r) {
      float t0 = __shfl(acc0[4][r], (agrp << 4) | 0);
      float t1 = __shfl(acc0[4][r], (agrp << 4) | 1);
      float ls = __shfl(acc0[4][r], (agrp << 4) | 2);
      size_t rp = (pbase + wave * 16 + agrp * 4 + r) * 68;
#pragma unroll
      for (int dc = 0; dc < 4; ++dc) part[rp + dc * 16 + arow] = acc0[dc][r];
      if (arow == 0) { part[rp + 64] = t0 + t1; part[rp + 65] = ls; }
    }
#pragma unroll
    for (int r = 0; r < 4; ++r) {
      float t0 = __shfl(acc1[4][r], (agrp << 4) | 0);
      float t1 = __shfl(acc1[4][r], (agrp << 4) | 1);
      float ls = __shfl(acc1[4][r], (agrp << 4) | 2);
      size_t rp = (pbase + 64 + wave * 16 + agrp * 4 + r) * 68;
#pragma unroll
      for (int dc = 0; dc < 4; ++dc) part[rp + dc * 16 + arow] = acc1[dc][r];
      if (arow == 0) { part[rp + 64] = t0 + t1; part[rp + 65] = ls; }
    }
  }
}

// ---------------------------------------------------------------------------
// Kernel 4: merge 4-way split-k partials (exact sums, m == 0), mean over
// heads, Lorentz normalization. One wave per (b,s); lane = space dim d.
// ---------------------------------------------------------------------------
__global__ __launch_bounds__(256) void finalize_kernel(
    const float* __restrict__ part, float* __restrict__ out)
{
  const int tid  = threadIdx.x;
  const int lane = tid & 63;
  const int gw = blockIdx.x * 4 + (tid >> 6);
  const int b = gw >> 11, si = gw & (SEQ - 1);
  const int qT = si >> 7, row = si & 127;

  float vsum = 0.f, tsum = 0.f;
#pragma unroll
  for (int h = 0; h < NH; ++h) {
    float Ah = 0.f, Th = 0.f, Lh = 0.f;
#pragma unroll
    for (int hf = 0; hf < 4; ++hf) {
      size_t rb = ((size_t)((((b * NH + h) * 16 + qT) * 4 + hf)) * 128 + row) * 68;
      Ah += part[rb + lane];
      Th += part[rb + 64];
      Lh += part[rb + 65];
    }
    float inv = 1.0f / Lh;
    vsum = fmaf(Ah, inv, vsum);
    tsum = fmaf(Th, inv, tsum);
  }
  float ave  = vsum * 0.125f;
  float tave = tsum * 0.125f;
  float contrib = ave * ave;
  if (lane == 0) contrib -= tave * tave;
  contrib += __shfl_xor(contrib, 1);
  contrib += __shfl_xor(contrib, 2);
  contrib += __shfl_xor(contrib, 4);
  contrib += __shfl_xor(contrib, 8);
  contrib += __shfl_xor(contrib, 16);
  contrib += __shfl_xor(contrib, 32);
  float denom = sqrtf(fmaxf(fabsf(contrib), 1e-8f));
  size_t ob = ((size_t)b * SEQ + si) * (size_t)DD;
  out[ob + 1 + lane] = ave / denom;
  if (lane == 0) out[ob] = tave / denom;
}

// ---------------------------------------------------------------------------
extern "C" void kernel_launch(void* const* d_in, const int* in_sizes, int n_in,
                              void* d_out, int out_size, void* d_ws, size_t ws_size,
                              hipStream_t stream) {
  const float* Xq  = (const float*)d_in[0];
  const float* Xs  = (const float*)d_in[1];
  const float* Wq  = (const float*)d_in[2];
  const float* Bq  = (const float*)d_in[3];
  const float* Wk  = (const float*)d_in[4];
  const float* Bk  = (const float*)d_in[5];
  const float* Wv  = (const float*)d_in[6];
  const float* Bv  = (const float*)d_in[7];
  const float* scale = (const float*)d_in[8];
  float* out = (float*)d_out;

  char* p = (char*)d_ws;

  // Region 0 (71.3 MB): partials, overlapped with bf16 X/W copies and vs
  // (all consumed before attn writes part).
  float* part = (float*)p;
  us* Xqb   = (us*)p;
  us* Xsb   = (us*)(p + 16777216);
  us* Wqb16 = (us*)(p + 33554432);
  us* Wkb16 = (us*)(p + 34078720);
  us* Wvb16 = (us*)(p + 34603008);
  us* vsb   = (us*)(p + 35651584);                 // 8.4MB, ends 44.0MB < 71.3MB
  p += (size_t)32 * 16 * 4 * 128 * 68 * 4;         // 71,303,168
  us* qsb = (us*)p; p += (size_t)NROW * 64 * 2;
  us* ksb = (us*)p; p += (size_t)NROW * 64 * 2;
  us* vTb = (us*)p; p += (size_t)NROW * 64 * 2;
  unsigned int* qtaw = (unsigned int*)p; p += (size_t)NROW * 4;
  unsigned int* ktaw = (unsigned int*)p; p += (size_t)NROW * 4;
  us* vtcw = (us*)p; p += (size_t)NROW * 2 * 2;

  tobf16_kernel<<<dim3(1024, 5), 256, 0, stream>>>(
      Xq, Xs, Wq, Wk, Wv, Xqb, Xsb, Wqb16, Wkb16, Wvb16);
  proj_kernel<<<dim3(1024, 1, 3), 256, 0, stream>>>(
      Xqb, Xsb, Wqb16, Wkb16, Wvb16, Bq, Bk, Bv, scale,
      qsb, qtaw, ksb, ktaw, vsb, vtcw);
  transpose_v_kernel<<<dim3(SEQ / 64, BATCH * NH), 256, 0, stream>>>(vsb, vTb);
  attn_kernel<<<dim3(1024), 256, 0, stream>>>(
      qsb, qtaw, ksb, ktaw, vTb, vtcw, part);
  finalize_kernel<<<(BATCH * SEQ) / 4, 256, 0, stream>>>(part, out);
}

// Round 10
// 100.322 us; speedup vs baseline: 1.0312x; 1.0312x over previous
//
#include <hip/hip_runtime.h>

// Problem constants
#define BATCH 4
#define SEQ   2048
#define INC   512
#define NH    8
#define OUTC  64      // space dim; head dim = 65
#define DD    65
#define NROW  (BATCH * NH * SEQ)   // 65536

typedef float f32x4 __attribute__((ext_vector_type(4)));
typedef short short8 __attribute__((ext_vector_type(8)));
typedef short short4v __attribute__((ext_vector_type(4)));
typedef unsigned short us;

static __device__ __forceinline__ us f2b(float f) {
  unsigned int u = __float_as_uint(f);
  u = (u + 0x7FFFu + ((u >> 16) & 1u)) >> 16;   // RNE f32->bf16
  return (us)u;
}
static __device__ __forceinline__ float b2f(us h) {
  return __uint_as_float(((unsigned int)h) << 16);
}
static __device__ __forceinline__ unsigned int pk2(float lo, float hi) {
  unsigned int r;
  asm("v_cvt_pk_bf16_f32 %0, %1, %2" : "=v"(r) : "v"(lo), "v"(hi));
  return r;
}
static __device__ __forceinline__ short8 mk8(unsigned int a, unsigned int b,
                                             unsigned int c, unsigned int d) {
  union { unsigned int u[4]; short8 s; } x;
  x.u[0] = a; x.u[1] = b; x.u[2] = c; x.u[3] = d;
  return x.s;
}

#define GLDS(g, l) __builtin_amdgcn_global_load_lds( \
    (const __attribute__((address_space(1))) void*)(g), \
    (__attribute__((address_space(3))) void*)(l), 16, 0, 0)
#define SB() __builtin_amdgcn_sched_barrier(0)

// ---------------------------------------------------------------------------
// Kernel 0: f32 -> bf16 conversion for X (both) and W (all three).
// ---------------------------------------------------------------------------
__global__ __launch_bounds__(256) void tobf16_kernel(
    const float* __restrict__ Xq, const float* __restrict__ Xs,
    const float* __restrict__ Wq, const float* __restrict__ Wk,
    const float* __restrict__ Wv,
    us* __restrict__ dXq, us* __restrict__ dXs,
    us* __restrict__ dWq, us* __restrict__ dWk, us* __restrict__ dWv)
{
  const int which = blockIdx.y;
  const float* src;
  us* dst;
  int n;
  switch (which) {
    case 0: src = Xq; dst = dXq; n = BATCH * SEQ * INC; break;
    case 1: src = Xs; dst = dXs; n = BATCH * SEQ * INC; break;
    case 2: src = Wq; dst = dWq; n = NH * OUTC * INC; break;
    case 3: src = Wk; dst = dWk; n = NH * OUTC * INC; break;
    default: src = Wv; dst = dWv; n = NH * OUTC * INC; break;
  }
  for (long i = (long)blockIdx.x * 256 + threadIdx.x; i * 4 < n;
       i += (long)gridDim.x * 256) {
    f32x4 v = *(const f32x4*)(src + i * 4);
    short4v o;
    o[0] = (short)f2b(v[0]); o[1] = (short)f2b(v[1]);
    o[2] = (short)f2b(v[2]); o[3] = (short)f2b(v[3]);
    *(short4v*)(dst + i * 4) = o;
  }
}

// ---------------------------------------------------------------------------
// Kernel 1: per-head projections, GLDS double-buffered.
//   Q (which==0): space part PRE-SCALED by al2 = (2/scale)*log2e; qta u32
//                 packs (qh | ql<<16) of al2*t.
//   K (which==1): kta u32 = (-kh) | (-kl)<<16 (raw t).
//   V (which==2): vtc bf16 planes {hi, lo} of raw t.
// ---------------------------------------------------------------------------
__global__ __launch_bounds__(256) void proj_kernel(
    const us* __restrict__ Xqb, const us* __restrict__ Xsb,
    const us* __restrict__ Wqb, const us* __restrict__ Wkb, const us* __restrict__ Wvb,
    const float* __restrict__ Bq, const float* __restrict__ Bk, const float* __restrict__ Bv,
    const float* __restrict__ scale_p,
    us* __restrict__ qs, unsigned int* __restrict__ qta,
    us* __restrict__ ks, unsigned int* __restrict__ kta,
    us* __restrict__ vs, us* __restrict__ vtc)
{
  const int which = blockIdx.z;
  const us* X = (which == 0) ? Xqb : Xsb;
  const us* W = (which == 0) ? Wqb : (which == 1 ? Wkb : Wvb);
  const float* Bb = (which == 0) ? Bq : (which == 1 ? Bk : Bv);
  us* outs = (which == 0) ? qs : (which == 1 ? ks : vs);
  const float al2 = (2.0f / scale_p[0]) * 1.44269504088896f;
  const float oscale = (which == 0) ? al2 : 1.0f;

  const int lin = blockIdx.x;                    // 0..1023
  const int h   = (lin >> 3) & 7;
  const int m0  = (((lin >> 6) << 3) | (lin & 7)) * 64;
  const int n0  = h * 64;

  __shared__ alignas(16) us lX[2][64 * 64];
  __shared__ alignas(16) us lW[2][64 * 64];

  const int tid  = threadIdx.x;
  const int lane = tid & 63;
  const int wave = tid >> 6;
  const int arow = lane & 15;
  const int agrp = lane >> 4;
  const int rl   = lane >> 3;
  const int chx  = ((lane & 7) ^ rl) * 8;
  const int r0   = wave * 8 + rl;
  const int r1   = r0 + 32;

#define PSTAGE(buf, k0) do { \
    GLDS(X + (size_t)(m0 + r0) * INC + (k0) + chx, &lX[buf][wave * 512]); \
    GLDS(X + (size_t)(m0 + r1) * INC + (k0) + chx, &lX[buf][2048 + wave * 512]); \
    GLDS(W + (size_t)(n0 + r0) * INC + (k0) + chx, &lW[buf][wave * 512]); \
    GLDS(W + (size_t)(n0 + r1) * INC + (k0) + chx, &lW[buf][2048 + wave * 512]); \
  } while (0)

  f32x4 acc[4] = {};
  PSTAGE(0, 0);

  for (int kk = 0; kk < 8; ++kk) {
    const int cur = kk & 1;
    if (kk < 7) {
      PSTAGE(cur ^ 1, (kk + 1) * 64);
      asm volatile("s_waitcnt vmcnt(4)");
    } else {
      asm volatile("s_waitcnt vmcnt(0)");
    }
    __builtin_amdgcn_s_barrier();
#pragma unroll
    for (int kc = 0; kc < 2; ++kc) {
      short8 af = *(const short8*)&lX[cur][(wave * 16 + arow) * 64 + (((kc * 4 + agrp) ^ (arow & 7)) * 8)];
#pragma unroll
      for (int c = 0; c < 4; ++c) {
        short8 bf = *(const short8*)&lW[cur][(c * 16 + arow) * 64 + (((kc * 4 + agrp) ^ (arow & 7)) * 8)];
        acc[c] = __builtin_amdgcn_mfma_f32_16x16x32_bf16(af, bf, acc[c], 0, 0, 0);
      }
    }
    __builtin_amdgcn_s_barrier();
  }

  float bcol[4];
#pragma unroll
  for (int c = 0; c < 4; ++c) bcol[c] = Bb[n0 + c * 16 + arow];
#pragma unroll
  for (int r = 0; r < 4; ++r) {
    float s2 = 0.f;
#pragma unroll
    for (int c = 0; c < 4; ++c) {
      float v = acc[c][r] + bcol[c];
      acc[c][r] = v;
      s2 += v * v;
    }
    s2 += __shfl_xor(s2, 1); s2 += __shfl_xor(s2, 2);
    s2 += __shfl_xor(s2, 4); s2 += __shfl_xor(s2, 8);
    float tv = sqrtf(s2 + 1.0f);
    int gs = m0 + wave * 16 + agrp * 4 + r;
    int bi = gs >> 11, si = gs & (SEQ - 1);
    size_t rowbase = (size_t)(bi * NH + h) * SEQ + si;
    size_t obase = rowbase * 64;
#pragma unroll
    for (int c = 0; c < 4; ++c) outs[obase + c * 16 + arow] = f2b(oscale * acc[c][r]);
    if (arow == 0) {
      if (which == 0) {
        float st = al2 * tv;
        us qh = f2b(st);
        us ql = f2b(st - b2f(qh));
        qta[rowbase] = (unsigned int)qh | ((unsigned int)ql << 16);
      } else {
        us th = f2b(tv);
        us tl = f2b(tv - b2f(th));
        if (which == 1) {
          kta[rowbase] = (unsigned int)(us)(th ^ 0x8000)
                       | ((unsigned int)(us)(tl ^ 0x8000) << 16);
        } else {
          vtc[rowbase] = th;
          vtc[NROW + rowbase] = tl;
        }
      }
    }
  }
}

// ---------------------------------------------------------------------------
// Kernel 2: transpose V space-part per (b,h): [S,64] -> [64,S] with a
// PERMUTED k-order inside each 64-block: position p = (sc&1)*32 + (jj>>2)*16
// + (sc>>2)*8 + ((sc>>1)&1)*4 + (jj&3) for original k = sc*8+jj. Each lane's
// own QK^T outputs then form the PV A-fragment directly (in-register P).
// ---------------------------------------------------------------------------
__global__ __launch_bounds__(256) void transpose_v_kernel(
    const us* __restrict__ vs, us* __restrict__ vT)
{
  const int bh = blockIdx.y;
  const int s0 = blockIdx.x * 64;
  __shared__ us lT[64 * 80];
  const int tid = threadIdx.x;
#pragma unroll
  for (int u0 = 0; u0 < 2; ++u0) {
    int u = tid + u0 * 256;
    int row = u >> 3, ch = u & 7;
    short8 v = *(const short8*)&vs[((size_t)bh * SEQ + s0 + row) * 64 + ch * 8];
    *(short8*)&lT[row * 80 + ch * 8] = v;
  }
  __syncthreads();
#pragma unroll
  for (int u0 = 0; u0 < 2; ++u0) {
    int u = tid + u0 * 256;
    int o = u >> 3, sc = u & 7;
    short4v w0, w1;
#pragma unroll
    for (int j = 0; j < 4; ++j) w0[j] = (short)lT[(sc * 8 + j) * 80 + o];
#pragma unroll
    for (int j = 0; j < 4; ++j) w1[j] = (short)lT[(sc * 8 + 4 + j) * 80 + o];
    const int base0 = (sc & 1) * 32 + (sc >> 2) * 8 + ((sc >> 1) & 1) * 4;
    us* dst = vT + ((size_t)bh * 64 + o) * SEQ + s0;
    *(short4v*)(dst + base0) = w0;
    *(short4v*)(dst + base0 + 16) = w1;
  }
}

// ---------------------------------------------------------------------------
// Kernel 3: 2-way split-k causal flash attention, KBLK=64, QBLK=64,
// 1024 blocks. In-register P (permuted V^T), pre-scaled Q (P = exp2(sS)
// directly), m == 0 always -> exact-sum merge.
// NOTE: __launch_bounds__(256) WITHOUT min-waves — the (256,4) variant
// (VGPR cap 128) miscompiled/NaN'd in round 9; round 8 passed with this
// exact in-reg-P code pattern compiled unconstrained.
// vmcnt queue: prologue [Q(3), aug(8), G0(4)]; steady state after issuing
// G_{t+1}: [G_t(4), aug_t(8), G_{t+1}(4)] -> wait vmcnt(12); last tile
// [G(4), aug(8)] -> vmcnt(8); it==0 -> vmcnt(4).
// ---------------------------------------------------------------------------
__global__ __launch_bounds__(256) void attn_kernel(
    const us* __restrict__ qs, const unsigned int* __restrict__ qta,
    const us* __restrict__ ks, const unsigned int* __restrict__ kta,
    const us* __restrict__ vT, const us* __restrict__ vtc,
    float* __restrict__ part)
{
  // XCD-aware swizzle: 32 blocks of one bh land on one XCD.
  const int f = blockIdx.x;
  const int xcd = f & 7, idx = f >> 3;
  const int bh = xcd * 4 + (idx >> 5);
  const int inner = idx & 31;
  const int xb = inner >> 1;
  const int hf = inner & 1;

  __shared__ alignas(16) us lK[2][64 * 64];
  __shared__ alignas(16) us lV[2][64 * 64];

  const int tid  = threadIdx.x;
  const int lane = tid & 63;
  const int wave = tid >> 6;
  const int arow = lane & 15;
  const int agrp = lane >> 4;

  const size_t bhbase = (size_t)bh * SEQ;
  const us* kgp = ks + bhbase * 64;
  const us* vgp = vT + (size_t)bh * 64 * SEQ;
  const unsigned int* ktp = kta + bhbase;
  const us* vtp = vtc + (size_t)(arow & 1) * NROW + bhbase;

  const int rl    = lane >> 3;
  const int chx   = ((lane & 7) ^ rl) * 8;
  const int r0s   = wave * 8 + rl;
  const int r1s   = r0s + 32;
  const int dsl0  = (agrp ^ (arow & 7)) * 8;
  const int dsl1  = ((4 + agrp) ^ (arow & 7)) * 8;
  const int dslV0 = ((agrp * 2) ^ (arow & 7)) * 8;       // kc=0
  const int dslV1 = ((agrp * 2 + 1) ^ (arow & 7)) * 8;   // kc=1

#define ASTAGE(buf, t64) do { \
    const int kk = (t64) * 64; \
    GLDS(kgp + (size_t)(kk + r0s) * 64 + chx, &lK[buf][wave * 512]); \
    GLDS(kgp + (size_t)(kk + r1s) * 64 + chx, &lK[buf][2048 + wave * 512]); \
    GLDS(vgp + (size_t)r0s * SEQ + kk + chx, &lV[buf][wave * 512]); \
    GLDS(vgp + (size_t)r1s * SEQ + kk + chx, &lV[buf][2048 + wave * 512]); \
  } while (0)

  short8 ones8, zero8 = {};
#pragma unroll
  for (int j = 0; j < 8; ++j) ones8[j] = (short)0x3F80;

  for (int seg = 0; seg < 2; ++seg) {
    const int qb = seg ? (31 - xb) : xb;
    const int q0 = qb * 64;
    const int c0 = (qb + 2) >> 1;           // ceil((qb+1)/2)
    const int t_lo = hf ? c0 : 0;
    const int t_hi = hf ? (qb + 1) : c0;
    const int nt = t_hi - t_lo;
    const int wq = wave * 16 + arow;

    f32x4 acc[5] = {};

    if (nt > 0) {
      // Q fragments + time terms FIRST (keeps the GLDS queue tail clean)
      const us* qp = qs + (bhbase + q0 + wq) * 64;
      short8 qf0 = *(const short8*)(qp + agrp * 8);
      short8 qf1 = *(const short8*)(qp + 32 + agrp * 8);
      unsigned int qw = qta[bhbase + q0 + wq];
      short8 qf2 = {};
      if (agrp == 0) {
        qf2[0] = (short)(qw & 0xFFFFu);
        qf2[1] = (short)(qw & 0xFFFFu);
        qf2[2] = (short)(qw >> 16);
      }

      // aug regs for first tile (4 + 4 = 8 VMEM)
      unsigned int ka[4];
      short4v vaA[2], vaB[2];
      {
        const int kk = t_lo * 64;
#pragma unroll
        for (int c = 0; c < 4; ++c) ka[c] = ktp[kk + c * 16 + arow];
#pragma unroll
        for (int kc = 0; kc < 2; ++kc) {
          vaA[kc] = *(const short4v*)(vtp + kk + kc * 32 + agrp * 4);
          vaB[kc] = *(const short4v*)(vtp + kk + kc * 32 + 16 + agrp * 4);
        }
      }
      SB();
      ASTAGE(0, t_lo);
      SB();

      for (int it = 0; it < nt; ++it) {
        const int t = t_lo + it;
        const int cur = it & 1;
        if (it < nt - 1) {
          ASTAGE(cur ^ 1, t + 1);
          SB();
          if (it == 0) asm volatile("s_waitcnt vmcnt(4)");
          else         asm volatile("s_waitcnt vmcnt(12)");
        } else {
          SB();
          if (nt > 1) asm volatile("s_waitcnt vmcnt(8)");
          else        asm volatile("s_waitcnt vmcnt(0)");
        }
        SB();
        __builtin_amdgcn_s_barrier();

        const us* Kb = lK[cur];
        const us* Vb = lV[cur];

        // ---- S^T = K' Q'^T (augmented: includes -qt*kt hi/lo) ----
        f32x4 sS[4] = {};
        __builtin_amdgcn_s_setprio(1);
#pragma unroll
        for (int c = 0; c < 4; ++c) {
          short8 kf = *(const short8*)&Kb[(c * 16 + arow) * 64 + dsl0];
          sS[c] = __builtin_amdgcn_mfma_f32_16x16x32_bf16(kf, qf0, sS[c], 0, 0, 0);
        }
#pragma unroll
        for (int c = 0; c < 4; ++c) {
          short8 kf = *(const short8*)&Kb[(c * 16 + arow) * 64 + dsl1];
          sS[c] = __builtin_amdgcn_mfma_f32_16x16x32_bf16(kf, qf1, sS[c], 0, 0, 0);
        }
#pragma unroll
        for (int c = 0; c < 4; ++c) {
          short8 kf2 = {};
          if (agrp == 0) {
            unsigned int w0 = ka[c];
            kf2[0] = (short)(w0 & 0xFFFFu);
            kf2[1] = (short)(w0 >> 16);
            kf2[2] = (short)(w0 & 0xFFFFu);
          }
          sS[c] = __builtin_amdgcn_mfma_f32_16x16x32_bf16(kf2, qf2, sS[c], 0, 0, 0);
        }
        __builtin_amdgcn_s_setprio(0);

        // ---- P = exp2(logit) (Q pre-scaled); causal mask -> exact 0 ----
#pragma unroll
        for (int c = 0; c < 4; ++c)
#pragma unroll
          for (int r = 0; r < 4; ++r)
            sS[c][r] = exp2f(sS[c][r]);
        if (t == qb) {
#pragma unroll
          for (int c = 0; c < 4; ++c)
#pragma unroll
            for (int r = 0; r < 4; ++r)
              if (c * 16 + agrp * 4 + r > wq) sS[c][r] = 0.f;
        }

        // ---- PV, in-register P (permuted V^T matches lane-local packing) --
        __builtin_amdgcn_s_setprio(1);
#pragma unroll
        for (int kc = 0; kc < 2; ++kc) {
          short8 pf = mk8(pk2(sS[2*kc][0], sS[2*kc][1]),
                          pk2(sS[2*kc][2], sS[2*kc][3]),
                          pk2(sS[2*kc+1][0], sS[2*kc+1][1]),
                          pk2(sS[2*kc+1][2], sS[2*kc+1][3]));
          const int dsl = kc ? dslV1 : dslV0;
#pragma unroll
          for (int dc = 0; dc < 4; ++dc) {
            short8 vf = *(const short8*)&Vb[(dc * 16 + arow) * 64 + dsl];
            acc[dc] = __builtin_amdgcn_mfma_f32_16x16x32_bf16(pf, vf, acc[dc], 0, 0, 0);
          }
          short8 vf4;
          if (arow < 2) {
            *(short4v*)&vf4 = vaA[kc];
            *(((short4v*)&vf4) + 1) = vaB[kc];
          } else vf4 = (arow == 2) ? ones8 : zero8;
          acc[4] = __builtin_amdgcn_mfma_f32_16x16x32_bf16(pf, vf4, acc[4], 0, 0, 0);
        }
        __builtin_amdgcn_s_setprio(0);

        // aug prefetch for next tile (in flight across the barrier)
        SB();
        if (it + 1 < nt) {
          const int kk = (t + 1) * 64;
#pragma unroll
          for (int c = 0; c < 4; ++c) ka[c] = ktp[kk + c * 16 + arow];
#pragma unroll
          for (int kc = 0; kc < 2; ++kc) {
            vaA[kc] = *(const short4v*)(vtp + kk + kc * 32 + agrp * 4);
            vaB[kc] = *(const short4v*)(vtp + kk + kc * 32 + 16 + agrp * 4);
          }
        }
        SB();
        __builtin_amdgcn_s_barrier();   // reads done: safe to overwrite other buf
      }
    }

    // ---- epilogue: write un-normalized partial (zeros for empty seg) ----
    const size_t pb = ((size_t)(bh * 32 + qb) * 2 + hf) * 64;
#pragma unroll
    for (int r = 0; r < 4; ++r) {
      float t0 = __shfl(acc[4][r], (agrp << 4) | 0);
      float t1 = __shfl(acc[4][r], (agrp << 4) | 1);
      float ls = __shfl(acc[4][r], (agrp << 4) | 2);
      size_t rp = (pb + wave * 16 + agrp * 4 + r) * 68;
#pragma unroll
      for (int dc = 0; dc < 4; ++dc)
        part[rp + dc * 16 + arow] = acc[dc][r];
      if (arow == 0) {
        part[rp + 64] = t0 + t1;
        part[rp + 65] = ls;
      }
    }
  }
}

// ---------------------------------------------------------------------------
// Kernel 4: merge split-k partials (exact sums, m == 0), mean over heads,
// Lorentz normalization. One wave per (b,s); lane = space dim d.
// ---------------------------------------------------------------------------
__global__ __launch_bounds__(256) void finalize_kernel(
    const float* __restrict__ part, float* __restrict__ out)
{
  const int tid  = threadIdx.x;
  const int lane = tid & 63;
  const int gw = blockIdx.x * 4 + (tid >> 6);
  const int b = gw >> 11, si = gw & (SEQ - 1);
  const int qb = si >> 6, row = si & 63;

  float vsum = 0.f, tsum = 0.f;
#pragma unroll
  for (int h = 0; h < NH; ++h) {
    float Ah = 0.f, Th = 0.f, Lh = 0.f;
#pragma unroll
    for (int hf = 0; hf < 2; ++hf) {
      size_t rb = (((size_t)((b * NH + h) * 32 + qb) * 2 + hf) * 64 + row) * 68;
      Ah += part[rb + lane];
      Th += part[rb + 64];
      Lh += part[rb + 65];
    }
    float inv = 1.0f / Lh;
    vsum = fmaf(Ah, inv, vsum);
    tsum = fmaf(Th, inv, tsum);
  }
  float ave  = vsum * 0.125f;
  float tave = tsum * 0.125f;
  float contrib = ave * ave;
  if (lane == 0) contrib -= tave * tave;
  contrib += __shfl_xor(contrib, 1);
  contrib += __shfl_xor(contrib, 2);
  contrib += __shfl_xor(contrib, 4);
  contrib += __shfl_xor(contrib, 8);
  contrib += __shfl_xor(contrib, 16);
  contrib += __shfl_xor(contrib, 32);
  float denom = sqrtf(fmaxf(fabsf(contrib), 1e-8f));
  size_t ob = ((size_t)b * SEQ + si) * (size_t)DD;
  out[ob + 1 + lane] = ave / denom;
  if (lane == 0) out[ob] = tave / denom;
}

// ---------------------------------------------------------------------------
extern "C" void kernel_launch(void* const* d_in, const int* in_sizes, int n_in,
                              void* d_out, int out_size, void* d_ws, size_t ws_size,
                              hipStream_t stream) {
  const float* Xq  = (const float*)d_in[0];
  const float* Xs  = (const float*)d_in[1];
  const float* Wq  = (const float*)d_in[2];
  const float* Bq  = (const float*)d_in[3];
  const float* Wk  = (const float*)d_in[4];
  const float* Bk  = (const float*)d_in[5];
  const float* Wv  = (const float*)d_in[6];
  const float* Bv  = (const float*)d_in[7];
  const float* scale = (const float*)d_in[8];
  float* out = (float*)d_out;

  char* p = (char*)d_ws;

  // Region 0 (35.7 MB): partials, overlapped with bf16 X and W copies
  // (proj consumes Xb/Wb before attn writes part).
  float* part = (float*)p;
  us* Xqb   = (us*)p;
  us* Xsb   = (us*)(p + 16777216);
  us* Wqb16 = (us*)(p + 33554432);
  us* Wkb16 = (us*)(p + 34078720);
  us* Wvb16 = (us*)(p + 34603008);
  p += (size_t)1024 * 2 * 64 * 68 * 4;             // 35,651,584
  us* qsb = (us*)p; p += (size_t)NROW * 64 * 2;
  us* ksb = (us*)p; p += (size_t)NROW * 64 * 2;
  us* vsb = (us*)p; p += (size_t)NROW * 64 * 2;
  us* vTb = (us*)p; p += (size_t)NROW * 64 * 2;
  unsigned int* qtaw = (unsigned int*)p; p += (size_t)NROW * 4;
  unsigned int* ktaw = (unsigned int*)p; p += (size_t)NROW * 4;
  us* vtcw = (us*)p; p += (size_t)NROW * 2 * 2;

  tobf16_kernel<<<dim3(1024, 5), 256, 0, stream>>>(
      Xq, Xs, Wq, Wk, Wv, Xqb, Xsb, Wqb16, Wkb16, Wvb16);
  proj_kernel<<<dim3(1024, 1, 3), 256, 0, stream>>>(
      Xqb, Xsb, Wqb16, Wkb16, Wvb16, Bq, Bk, Bv, scale,
      qsb, qtaw, ksb, ktaw, vsb, vtcw);
  transpose_v_kernel<<<dim3(SEQ / 64, BATCH * NH), 256, 0, stream>>>(vsb, vTb);
  attn_kernel<<<dim3(1024), 256, 0, stream>>>(
      qsb, qtaw, ksb, ktaw, vTb, vtcw, part);
  finalize_kernel<<<(BATCH * SEQ) / 4, 256, 0, stream>>>(part, out);
}